// Round 2
// baseline (238.569 us; speedup 1.0000x reference)
//
#include <hip/hip_runtime.h>
#include <hip/hip_bf16.h>

// Problem constants (from reference)
#define HD 64
#define VOCAB 64
#define SEQ 48
#define MEMSLOTS 4
#define TSTRIDE 66   // table row stride in floats (64 data + 2 pad, keeps float2 alignment, breaks bank pow2)

using frag_ab = __attribute__((ext_vector_type(8))) short;   // 8 bf16
using frag_cd = __attribute__((ext_vector_type(4))) float;   // 4 fp32
typedef __attribute__((ext_vector_type(4))) float floatx4;

static __device__ inline unsigned short f2bf(float f) {
  // round-to-nearest-even fp32 -> bf16
  unsigned u = __float_as_uint(f);
  unsigned r = (u + 0x7fffu + ((u >> 16) & 1u)) >> 16;
  return (unsigned short)r;
}

// Kernel A: build fused first-layer tables in workspace.
// T1[v][j] = sum_k embed[v][k]*W1[j][k] + b1[j]          (query half)
// T2[v][j] = 0.25 * sum_k embed[v][k]*W1[j][64+k]        (memory half, mean folded)
__global__ void build_tables(const float* __restrict__ embed,
                             const float* __restrict__ W1,
                             const float* __restrict__ b1,
                             float* __restrict__ T) {
  int v = blockIdx.x;    // 0..63
  int j = threadIdx.x;   // 0..63
  const float* e = embed + v * HD;
  const float* w1r = W1 + j * (2 * HD);
  float s1 = 0.f, s2 = 0.f;
  for (int k = 0; k < HD; ++k) {
    float ev = e[k];              // uniform per block -> scalar loads
    s1 += ev * w1r[k];
    s2 += ev * w1r[HD + k];
  }
  T[v * TSTRIDE + j] = s1 + b1[j];
  T[VOCAB * TSTRIDE + v * TSTRIDE + j] = 0.25f * s2;
}

// Kernel B: per 16-row batch per wave:
//  gather+sum 5 table rows from LDS -> pre(16 k-slots/lane in MFMA A layout)
//  relu -> bf16 -> 2 x mfma_f32_16x16x32_bf16 per n-tile (4 n-tiles)
//  store fp32 C fragments (coalesced 4x64B segments per store)
__global__ __launch_bounds__(256, 4) void lru_main(
    const int* __restrict__ seqs, const int* __restrict__ qtok,
    const float* __restrict__ W2, const float* __restrict__ b2,
    const float* __restrict__ T, float* __restrict__ out, int nbatch) {
  __shared__ float sT[2 * VOCAB * TSTRIDE];   // 33792 B: T1 then T2

  // cooperative stage of both tables (contiguous in ws)
  {
    const floatx4* src = (const floatx4*)T;
    floatx4* dst = (floatx4*)sT;
    const int n4 = 2 * VOCAB * TSTRIDE / 4;   // 2112
    for (int i = threadIdx.x; i < n4; i += blockDim.x) dst[i] = src[i];
  }
  __syncthreads();

  const int lane = threadIdx.x & 63;
  const int quad = lane >> 4;
  const int m    = lane & 15;
  const int k0   = quad * 8;

  // B fragments: B[k][n] with n = lane&15 (+16*t), k = s*32 + quad*8 + j. Held for the whole wave.
  frag_ab bf[4][2];
  for (int t = 0; t < 4; ++t)
    for (int s = 0; s < 2; ++s) {
      const float* w2r = W2 + (t * 16 + m) * HD + s * 32 + k0;
      for (int j = 0; j < 8; ++j) bf[t][s][j] = (short)f2bf(w2r[j]);
    }
  float b2v[4];
  for (int t = 0; t < 4; ++t) b2v[t] = b2[t * 16 + m];

  const int wave = blockIdx.x * (blockDim.x >> 6) + (threadIdx.x >> 6);
  const int nw   = gridDim.x * (blockDim.x >> 6);

  const float* T1 = sT;
  const float* T2 = sT + VOCAB * TSTRIDE;

  for (int b = wave; b < nbatch; b += nw) {
    const int rb  = b * 16;
    const int row = rb + m;                 // all 4 quads redundantly load row m's tokens
    const int q   = qtok[row];
    const int* sp = seqs + row * SEQ;
    const int ta  = sp[43];                 // col 43
    const int4 tb = *(const int4*)(sp + 44); // cols 44,45,46,(47 unused); 16B-aligned

    // gather + sum 5 table rows at my 16 k-slots: k = k0+0..7 and 32+k0+0..7
    float2 a[8];
    {
      const float2* p1  = (const float2*)(T1 + q * TSTRIDE + k0);
      const float2* p1b = (const float2*)(T1 + q * TSTRIDE + 32 + k0);
      for (int c = 0; c < 4; ++c) { a[c] = p1[c]; a[4 + c] = p1b[c]; }
      const int toks[4] = {ta, tb.x, tb.y, tb.z};
      for (int u = 0; u < 4; ++u) {
        const float2* p2  = (const float2*)(T2 + toks[u] * TSTRIDE + k0);
        const float2* p2b = (const float2*)(T2 + toks[u] * TSTRIDE + 32 + k0);
        for (int c = 0; c < 4; ++c) {
          float2 x = p2[c], y = p2b[c];
          a[c].x += x.x; a[c].y += x.y;
          a[4 + c].x += y.x; a[4 + c].y += y.y;
        }
      }
    }

    // relu + bf16 pack into A fragments: A[m=lane&15][k=quad*8+j] (+32 for a1)
    frag_ab a0, a1;
    for (int c = 0; c < 4; ++c) {
      a0[2 * c]     = (short)f2bf(fmaxf(a[c].x, 0.f));
      a0[2 * c + 1] = (short)f2bf(fmaxf(a[c].y, 0.f));
      a1[2 * c]     = (short)f2bf(fmaxf(a[4 + c].x, 0.f));
      a1[2 * c + 1] = (short)f2bf(fmaxf(a[4 + c].y, 0.f));
    }

    frag_cd acc[4];
    for (int t = 0; t < 4; ++t) {
      acc[t] = (frag_cd){0.f, 0.f, 0.f, 0.f};
      acc[t] = __builtin_amdgcn_mfma_f32_16x16x32_bf16(a0, bf[t][0], acc[t], 0, 0, 0);
      acc[t] = __builtin_amdgcn_mfma_f32_16x16x32_bf16(a1, bf[t][1], acc[t], 0, 0, 0);
    }

    // C layout: col = lane&15, row = quad*4 + reg
    float* orow = out + (size_t)rb * HD;
    for (int t = 0; t < 4; ++t)
      for (int p = 0; p < 4; ++p)
        orow[(quad * 4 + p) * HD + t * 16 + m] = acc[t][p] + b2v[t];
  }
}

extern "C" void kernel_launch(void* const* d_in, const int* in_sizes, int n_in,
                              void* d_out, int out_size, void* d_ws, size_t ws_size,
                              hipStream_t stream) {
  const int*   seqs  = (const int*)d_in[0];
  const int*   qtok  = (const int*)d_in[1];
  const float* embed = (const float*)d_in[2];
  const float* W1    = (const float*)d_in[3];
  const float* b1    = (const float*)d_in[4];
  const float* W2    = (const float*)d_in[5];
  const float* b2    = (const float*)d_in[6];
  float* out = (float*)d_out;
  float* T   = (float*)d_ws;   // 2*64*66 floats = 33792 B

  const int B = in_sizes[1];        // number of rows (524288)
  const int nbatch = B / 16;

  build_tables<<<VOCAB, HD, 0, stream>>>(embed, W1, b1, T);
  lru_main<<<2048, 256, 0, stream>>>(seqs, qtok, W2, b2, T, out, nbatch);
}